// Round 19
// baseline (73.121 us; speedup 1.0000x reference)
//
#include <hip/hip_runtime.h>
#include <math.h>

#define N 8192
#define D 64

typedef short bf16x8 __attribute__((ext_vector_type(8)));
typedef float f32x4 __attribute__((ext_vector_type(4)));

__device__ __forceinline__ void gload_lds16(const void* g, void* l) {
    __builtin_amdgcn_global_load_lds(
        (const __attribute__((address_space(1))) void*)g,
        (__attribute__((address_space(3))) void*)l, 16, 0, 0);
}

// Convert fp32 -> bf16 of (sqrt(log2e)*x); nscl[i] = 0.5*||bf16(s*x)||^2 = log2e*||x||^2/2.
// Block 0 also zeroes the 6 accumulator slots + completion counter (8 words)
// EVERY call, so the fused finalize fires exactly once per launch (replay-safe).
__global__ __launch_bounds__(256) void convert_norm(
        const float* __restrict__ X, const float* __restrict__ Y,
        const float* __restrict__ Z,
        unsigned short* __restrict__ bmat, float* __restrict__ nscl,
        float* __restrict__ accs) {
    if (blockIdx.x == 0 && threadIdx.x < 8) accs[threadIdx.x] = 0.0f;
    int wid  = blockIdx.x * 4 + (threadIdx.x >> 6);
    int lane = threadIdx.x & 63;
    int mat  = wid >> 13;
    int row  = wid & 8191;
    const float* src = (mat == 0) ? X : (mat == 1 ? Y : Z);
    float v = src[row * D + lane] * 1.2011224087864498f;  // sqrt(log2(e))
    unsigned int bits = __builtin_bit_cast(unsigned int, v);
    unsigned short us = (unsigned short)((bits + 0x7FFFu + ((bits >> 16) & 1u)) >> 16);
    float f = __builtin_bit_cast(float, (unsigned int)us << 16);
    bmat[(size_t)mat * (N * D) + row * D + lane] = us;
    float sq = f * f;
    #pragma unroll
    for (int off = 32; off; off >>= 1) sq += __shfl_xor(sq, off);
    if (lane == 0) nscl[mat * N + row] = sq * 0.5f;
}

// EXACT R18 gram loop (measured floor of this class: 128-row block, 512 thr /
// 8 waves in 4x2, grid 768 = 3 blocks/CU, triple-buffered 8 KB ring + 16 KB
// cb strip in LDS, XOR swizzle, per-iter VMEM = 1 stage load -> steady
// vmcnt(1) + raw barrier, pipelined epilogue thr=-30, setprio around MFMA).
// ONLY change: the last-finishing block (atomic counter) computes the final
// scalar in-kernel, eliminating the separate init/finalize launches.
__global__ __launch_bounds__(512, 6) void gram_kernel(
        const unsigned short* __restrict__ bmat,
        const float* __restrict__ nscl,
        float* accs, unsigned int* cnt, float* out) {
    const int PA[6] = {0, 2, 0, 0, 1, 1};  // X,Z,X,X,Y,Y
    const int PB[6] = {0, 2, 2, 1, 1, 2};  // X,Z,Z,Y,Y,Z
    int p  = blockIdx.y;
    int bx = blockIdx.x;          // 0..127
    int ti = bx >> 1;             // row strip (128 rows)
    int tc = bx & 1;              // col half (4096 cols)

    const unsigned short* A = bmat + (size_t)PA[p] * (N * D);
    const unsigned short* B = bmat + (size_t)PB[p] * (N * D);
    const float* ca = nscl + PA[p] * N;
    const float* cb = nscl + PB[p] * N;

    int tid = threadIdx.x;
    int w = tid >> 6, lane = tid & 63;   // w = 0..7
    int wr = w >> 1, wc = w & 1;         // 4 row-groups x 2 col-groups
    int rowBase = ti * 128 + wr * 32;
    int r = lane & 15, q = lane >> 4, r7 = lane & 7;

    // 24 KB tile ring + 16 KB cb strip
    __shared__ __align__(128) char lds[3 * 8192 + 16384];
    __shared__ float wsum[8];
    const float* cbLds = (const float*)(lds + 24576);

    int sub = w * 1024;                   // wave stages 1 KB (8 cols) per tile
    int laneoff = ((lane >> 3) << 7) + ((r7 ^ (lane >> 3)) << 4);
    const char* gB  = (const char*)(B + (size_t)(tc * 4096) * D);
    const char* gCb = (const char*)(cb + tc * 4096);

    // Swizzled ds_read offsets (measured conflict-free R6-R18)
    int off0 = wc * 4096 + r * 128 + ((q ^ r7) << 4);        // kc=0
    int off1 = wc * 4096 + r * 128 + (((4 + q) ^ r7) << 4);  // kc=1

    // Prologue issue order (gload_lds preserves program order):
    // stage0, cb strip (2/wave), stage1 -> at iter 0, vmcnt(1) retires
    // stage0 + cb, leaving only stage1 in flight.
    {
        gload_lds16(gB + sub + laneoff, lds + sub);
        int csub = w * 2048;              // wave's 2 KB of the cb strip
        gload_lds16(gCb + csub + lane * 16,        lds + 24576 + csub);
        gload_lds16(gCb + csub + 1024 + lane * 16, lds + 24576 + csub + 1024);
        gload_lds16(gB + 8192 + sub + laneoff, lds + 8192 + sub);
    }

    // Loop-invariant A fragments and negated row-norm constants
    bf16x8 afrag[2][2];
    #pragma unroll
    for (int mt = 0; mt < 2; ++mt)
        #pragma unroll
        for (int kc = 0; kc < 2; ++kc)
            afrag[mt][kc] = *reinterpret_cast<const bf16x8*>(
                A + (size_t)(rowBase + mt * 16 + r) * D + kc * 32 + q * 8);
    f32x4 ncam[2];
    #pragma unroll
    for (int mt = 0; mt < 2; ++mt)
        #pragma unroll
        for (int e = 0; e < 4; ++e)
            ncam[mt][e] = -ca[rowBase + mt * 16 + q * 4 + e];

    int cbIdx = wc * 32 + r;              // + t*64 per iter, +16 for cb1

    f32x4 lsum = (f32x4)0.0f;
    f32x4 acc0[2][2], acc1[2][2], acc2[2][2];

    // Epilogue of one acc set (register-only; max3-fusable triple tree)
    #define EPI(ACC)                                                          \
    {                                                                         \
        float e0 = fmaxf(fmaxf(ACC[0][0][0], ACC[0][0][1]), ACC[0][0][2]);    \
        float e1 = fmaxf(fmaxf(ACC[0][0][3], ACC[0][1][0]), ACC[0][1][1]);    \
        float e2 = fmaxf(fmaxf(ACC[0][1][2], ACC[0][1][3]), ACC[1][0][0]);    \
        float e3 = fmaxf(fmaxf(ACC[1][0][1], ACC[1][0][2]), ACC[1][0][3]);    \
        float e4 = fmaxf(fmaxf(ACC[1][1][0], ACC[1][1][1]), ACC[1][1][2]);    \
        float e5 = fmaxf(fmaxf(e0, e1), e2);                                  \
        float e6 = fmaxf(fmaxf(e3, e4), ACC[1][1][3]);                        \
        float em = fmaxf(e5, e6);                                             \
        if (__any(em > -30.0f)) {                                             \
            _Pragma("unroll")                                                 \
            for (int mt = 0; mt < 2; ++mt) {                                  \
                _Pragma("unroll")                                             \
                for (int nt = 0; nt < 2; ++nt) {                              \
                    f32x4 ex;                                                 \
                    _Pragma("unroll")                                         \
                    for (int e = 0; e < 4; ++e)                               \
                        ex[e] = __builtin_amdgcn_exp2f(ACC[mt][nt][e]);       \
                    lsum += ex;                                               \
                }                                                             \
            }                                                                 \
        }                                                                     \
    }

    // One pipeline stage for tile t: counted sync, cb from LDS, stage t+2
    // (1 load), ds_read tile, [previous tile's epilogue in the shadow],
    // init + prioritized MFMA cluster into ACC.
    #define GSTEP(RB, SB, ACC, DO_EPI, ACCP, TT, WAITN)                       \
    {                                                                         \
        asm volatile("s_waitcnt vmcnt(" #WAITN ")" ::: "memory");             \
        __builtin_amdgcn_s_barrier();                                         \
        asm volatile("" ::: "memory");                                        \
        float cb0 = cbLds[(TT) * 64 + cbIdx];                                 \
        float cb1 = cbLds[(TT) * 64 + cbIdx + 16];                            \
        int tn = ((TT) + 2 <= 63) ? ((TT) + 2) : 63;                          \
        gload_lds16(gB + (size_t)tn * 8192 + sub + laneoff, lds + (SB) + sub);\
        bf16x8 bf00 = *reinterpret_cast<const bf16x8*>(lds + (RB) + off0);    \
        bf16x8 bf01 = *reinterpret_cast<const bf16x8*>(lds + (RB) + off1);    \
        bf16x8 bf10 = *reinterpret_cast<const bf16x8*>(lds + (RB) + 2048 + off0); \
        bf16x8 bf11 = *reinterpret_cast<const bf16x8*>(lds + (RB) + 2048 + off1); \
        if (DO_EPI) EPI(ACCP);                                                \
        ACC[0][0] = ncam[0] - cb0; ACC[0][1] = ncam[0] - cb1;                 \
        ACC[1][0] = ncam[1] - cb0; ACC[1][1] = ncam[1] - cb1;                 \
        __builtin_amdgcn_s_setprio(1);                                        \
        ACC[0][0] = __builtin_amdgcn_mfma_f32_16x16x32_bf16(afrag[0][0], bf00, ACC[0][0], 0, 0, 0); \
        ACC[0][1] = __builtin_amdgcn_mfma_f32_16x16x32_bf16(afrag[0][0], bf10, ACC[0][1], 0, 0, 0); \
        ACC[1][0] = __builtin_amdgcn_mfma_f32_16x16x32_bf16(afrag[1][0], bf00, ACC[1][0], 0, 0, 0); \
        ACC[1][1] = __builtin_amdgcn_mfma_f32_16x16x32_bf16(afrag[1][0], bf10, ACC[1][1], 0, 0, 0); \
        ACC[0][0] = __builtin_amdgcn_mfma_f32_16x16x32_bf16(afrag[0][1], bf01, ACC[0][0], 0, 0, 0); \
        ACC[0][1] = __builtin_amdgcn_mfma_f32_16x16x32_bf16(afrag[0][1], bf11, ACC[0][1], 0, 0, 0); \
        ACC[1][0] = __builtin_amdgcn_mfma_f32_16x16x32_bf16(afrag[1][1], bf01, ACC[1][0], 0, 0, 0); \
        ACC[1][1] = __builtin_amdgcn_mfma_f32_16x16x32_bf16(afrag[1][1], bf11, ACC[1][1], 0, 0, 0); \
        __builtin_amdgcn_s_setprio(0);                                        \
    }

    // t = 0: ring slot 0; prologue order makes vmcnt(1) retire stage0+cb.
    GSTEP(0, 16384, acc0, false, acc0, 0, 1)
    // t = 1..63: steady-state vmcnt(1); 21 trips of 3 (slots 1,2,0)
    for (int trip = 0; trip < 21; ++trip) {
        int t1 = 1 + trip * 3;
        GSTEP(8192,  0,     acc1, true, acc0, t1,     1)
        GSTEP(16384, 8192,  acc2, true, acc1, t1 + 1, 1)
        GSTEP(0,     16384, acc0, true, acc2, t1 + 2, 1)
    }
    EPI(acc0)   // final tile's epilogue

    #undef GSTEP
    #undef EPI

    float ls = lsum[0] + lsum[1] + lsum[2] + lsum[3];
    #pragma unroll
    for (int off = 32; off; off >>= 1) ls += __shfl_xor(ls, off);
    if (lane == 0) wsum[w] = ls;
    __syncthreads();
    if (tid == 0) {
        float s = 0.0f;
        #pragma unroll
        for (int i = 0; i < 8; ++i) s += wsum[i];
        atomicAdd(&accs[p], s);
        __threadfence();
        unsigned old = atomicAdd(cnt, 1u);
        if (old == 768u - 1u) {
            // last block: all accs atomics globally visible; read coherently
            // via atomic RMW (cross-XCD safe) and finalize.
            __threadfence();
            double sv[6];
            #pragma unroll
            for (int i = 0; i < 6; ++i) sv[i] = (double)atomicAdd(&accs[i], 0.0f);
            double inv = 1.0 / (8192.0 * 8192.0 * 3.5449077018110318);
            double mxx = sv[0] * inv, mzz = sv[1] * inv, mxz = sv[2] * inv;
            double mxy = sv[3] * inv, myy = sv[4] * inv, myz = sv[5] * inv;
            double r1 = log(3.0 * sqrt(mxx * mzz + 1e-5) / (mxz + 1e-5));
            double r2 = log(3.0 * sqrt(myy * mzz + 1e-5) / (myz + 1e-5));
            double r3 = log(3.0 * sqrt(mxx * myy + 1e-5) / (mxy + 1e-5));
            out[0] = (float)(10.0 * r1 + r2 + 10.0 * r3);
        }
    }
}

extern "C" void kernel_launch(void* const* d_in, const int* in_sizes, int n_in,
                              void* d_out, int out_size, void* d_ws, size_t ws_size,
                              hipStream_t stream) {
    const float* X = (const float*)d_in[0];
    const float* Y = (const float*)d_in[1];
    const float* Z = (const float*)d_in[2];
    char* ws = (char*)d_ws;
    unsigned short* bmat = (unsigned short*)ws;                       // 3 MB
    float* nscl = (float*)(ws + (size_t)3 * N * D * 2);               // 3*8192 f32
    float* accs = (float*)(ws + (size_t)3 * N * D * 2 + (size_t)3 * N * 4); // 8 slots
    unsigned int* cnt = (unsigned int*)(accs + 6);
    float* out = (float*)d_out;

    hipLaunchKernelGGL(convert_norm, dim3(3 * N / 4), dim3(256), 0, stream,
                       X, Y, Z, bmat, nscl, accs);
    hipLaunchKernelGGL(gram_kernel, dim3(128, 6), dim3(512), 0, stream,
                       bmat, nscl, accs, cnt, out);
}

// Round 20
// 67.455 us; speedup vs baseline: 1.0840x; 1.0840x over previous
//
#include <hip/hip_runtime.h>
#include <math.h>

#define N 8192
#define D 64

typedef short bf16x8 __attribute__((ext_vector_type(8)));
typedef float f32x4 __attribute__((ext_vector_type(4)));

__device__ __forceinline__ void gload_lds16(const void* g, void* l) {
    __builtin_amdgcn_global_load_lds(
        (const __attribute__((address_space(1))) void*)g,
        (__attribute__((address_space(3))) void*)l, 16, 0, 0);
}

__global__ void init_accs(float* accs) {
    if (threadIdx.x < 6) accs[threadIdx.x] = 0.0f;
}

// Convert fp32 -> bf16 of (sqrt(log2e)*x); nscl[i] = 0.5*||bf16(s*x)||^2 = log2e*||x||^2/2.
__global__ __launch_bounds__(256) void convert_norm(
        const float* __restrict__ X, const float* __restrict__ Y,
        const float* __restrict__ Z,
        unsigned short* __restrict__ bmat, float* __restrict__ nscl) {
    int wid  = blockIdx.x * 4 + (threadIdx.x >> 6);
    int lane = threadIdx.x & 63;
    int mat  = wid >> 13;
    int row  = wid & 8191;
    const float* src = (mat == 0) ? X : (mat == 1 ? Y : Z);
    float v = src[row * D + lane] * 1.2011224087864498f;  // sqrt(log2(e))
    unsigned int bits = __builtin_bit_cast(unsigned int, v);
    unsigned short us = (unsigned short)((bits + 0x7FFFu + ((bits >> 16) & 1u)) >> 16);
    float f = __builtin_bit_cast(float, (unsigned int)us << 16);
    bmat[(size_t)mat * (N * D) + row * D + lane] = us;
    float sq = f * f;
    #pragma unroll
    for (int off = 32; off; off >>= 1) sq += __shfl_xor(sq, off);
    if (lane == 0) nscl[mat * N + row] = sq * 0.5f;
}

// Session-best configuration (R18, measured 56.5 us gram / 67.8 us total):
// 128-row block, 512 thr / 8 waves in 4x2, grid 768 = 3 blocks/CU,
// triple-buffered 8 KB tile ring + 16 KB cb strip in LDS, XOR store/read
// swizzle (conflict-free), per-iter VMEM = 1 stage load -> steady vmcnt(1)
// + raw s_barrier (counted ledger), tile-t epilogue (max-tree + exp,
// thr=-30) pipelined into tile-(t+1)'s ds-latency shadow via three named
// acc sets, s_setprio(1) around the MFMA cluster. Separate tiny init /
// finalize kernels — in-kernel fused finalize costs ~15 us (3x reproduced).
__global__ __launch_bounds__(512, 6) void gram_kernel(
        const unsigned short* __restrict__ bmat,
        const float* __restrict__ nscl,
        float* __restrict__ accs) {
    const int PA[6] = {0, 2, 0, 0, 1, 1};  // X,Z,X,X,Y,Y
    const int PB[6] = {0, 2, 2, 1, 1, 2};  // X,Z,Z,Y,Y,Z
    int p  = blockIdx.y;
    int bx = blockIdx.x;          // 0..127
    int ti = bx >> 1;             // row strip (128 rows)
    int tc = bx & 1;              // col half (4096 cols)

    const unsigned short* A = bmat + (size_t)PA[p] * (N * D);
    const unsigned short* B = bmat + (size_t)PB[p] * (N * D);
    const float* ca = nscl + PA[p] * N;
    const float* cb = nscl + PB[p] * N;

    int tid = threadIdx.x;
    int w = tid >> 6, lane = tid & 63;   // w = 0..7
    int wr = w >> 1, wc = w & 1;         // 4 row-groups x 2 col-groups
    int rowBase = ti * 128 + wr * 32;
    int r = lane & 15, q = lane >> 4, r7 = lane & 7;

    // 24 KB tile ring + 16 KB cb strip
    __shared__ __align__(128) char lds[3 * 8192 + 16384];
    __shared__ float wsum[8];
    const float* cbLds = (const float*)(lds + 24576);

    int sub = w * 1024;                   // wave stages 1 KB (8 cols) per tile
    int laneoff = ((lane >> 3) << 7) + ((r7 ^ (lane >> 3)) << 4);
    const char* gB  = (const char*)(B + (size_t)(tc * 4096) * D);
    const char* gCb = (const char*)(cb + tc * 4096);

    // Swizzled ds_read offsets (measured conflict-free R6-R18)
    int off0 = wc * 4096 + r * 128 + ((q ^ r7) << 4);        // kc=0
    int off1 = wc * 4096 + r * 128 + (((4 + q) ^ r7) << 4);  // kc=1

    // Prologue issue order (gload_lds preserves program order):
    // stage0, cb strip (2/wave), stage1 -> at iter 0, vmcnt(1) retires
    // stage0 + cb, leaving only stage1 in flight.
    {
        gload_lds16(gB + sub + laneoff, lds + sub);
        int csub = w * 2048;              // wave's 2 KB of the cb strip
        gload_lds16(gCb + csub + lane * 16,        lds + 24576 + csub);
        gload_lds16(gCb + csub + 1024 + lane * 16, lds + 24576 + csub + 1024);
        gload_lds16(gB + 8192 + sub + laneoff, lds + 8192 + sub);
    }

    // Loop-invariant A fragments and negated row-norm constants
    bf16x8 afrag[2][2];
    #pragma unroll
    for (int mt = 0; mt < 2; ++mt)
        #pragma unroll
        for (int kc = 0; kc < 2; ++kc)
            afrag[mt][kc] = *reinterpret_cast<const bf16x8*>(
                A + (size_t)(rowBase + mt * 16 + r) * D + kc * 32 + q * 8);
    f32x4 ncam[2];
    #pragma unroll
    for (int mt = 0; mt < 2; ++mt)
        #pragma unroll
        for (int e = 0; e < 4; ++e)
            ncam[mt][e] = -ca[rowBase + mt * 16 + q * 4 + e];

    int cbIdx = wc * 32 + r;              // + t*64 per iter, +16 for cb1

    f32x4 lsum = (f32x4)0.0f;
    f32x4 acc0[2][2], acc1[2][2], acc2[2][2];

    // Epilogue of one acc set (register-only; max3-fusable triple tree)
    #define EPI(ACC)                                                          \
    {                                                                         \
        float e0 = fmaxf(fmaxf(ACC[0][0][0], ACC[0][0][1]), ACC[0][0][2]);    \
        float e1 = fmaxf(fmaxf(ACC[0][0][3], ACC[0][1][0]), ACC[0][1][1]);    \
        float e2 = fmaxf(fmaxf(ACC[0][1][2], ACC[0][1][3]), ACC[1][0][0]);    \
        float e3 = fmaxf(fmaxf(ACC[1][0][1], ACC[1][0][2]), ACC[1][0][3]);    \
        float e4 = fmaxf(fmaxf(ACC[1][1][0], ACC[1][1][1]), ACC[1][1][2]);    \
        float e5 = fmaxf(fmaxf(e0, e1), e2);                                  \
        float e6 = fmaxf(fmaxf(e3, e4), ACC[1][1][3]);                        \
        float em = fmaxf(e5, e6);                                             \
        if (__any(em > -30.0f)) {                                             \
            _Pragma("unroll")                                                 \
            for (int mt = 0; mt < 2; ++mt) {                                  \
                _Pragma("unroll")                                             \
                for (int nt = 0; nt < 2; ++nt) {                              \
                    f32x4 ex;                                                 \
                    _Pragma("unroll")                                         \
                    for (int e = 0; e < 4; ++e)                               \
                        ex[e] = __builtin_amdgcn_exp2f(ACC[mt][nt][e]);       \
                    lsum += ex;                                               \
                }                                                             \
            }                                                                 \
        }                                                                     \
    }

    // One pipeline stage for tile t: counted sync, cb from LDS, stage t+2
    // (1 load), ds_read tile, [previous tile's epilogue in the shadow],
    // init + prioritized MFMA cluster into ACC.
    #define GSTEP(RB, SB, ACC, DO_EPI, ACCP, TT, WAITN)                       \
    {                                                                         \
        asm volatile("s_waitcnt vmcnt(" #WAITN ")" ::: "memory");             \
        __builtin_amdgcn_s_barrier();                                         \
        asm volatile("" ::: "memory");                                        \
        float cb0 = cbLds[(TT) * 64 + cbIdx];                                 \
        float cb1 = cbLds[(TT) * 64 + cbIdx + 16];                            \
        int tn = ((TT) + 2 <= 63) ? ((TT) + 2) : 63;                          \
        gload_lds16(gB + (size_t)tn * 8192 + sub + laneoff, lds + (SB) + sub);\
        bf16x8 bf00 = *reinterpret_cast<const bf16x8*>(lds + (RB) + off0);    \
        bf16x8 bf01 = *reinterpret_cast<const bf16x8*>(lds + (RB) + off1);    \
        bf16x8 bf10 = *reinterpret_cast<const bf16x8*>(lds + (RB) + 2048 + off0); \
        bf16x8 bf11 = *reinterpret_cast<const bf16x8*>(lds + (RB) + 2048 + off1); \
        if (DO_EPI) EPI(ACCP);                                                \
        ACC[0][0] = ncam[0] - cb0; ACC[0][1] = ncam[0] - cb1;                 \
        ACC[1][0] = ncam[1] - cb0; ACC[1][1] = ncam[1] - cb1;                 \
        __builtin_amdgcn_s_setprio(1);                                        \
        ACC[0][0] = __builtin_amdgcn_mfma_f32_16x16x32_bf16(afrag[0][0], bf00, ACC[0][0], 0, 0, 0); \
        ACC[0][1] = __builtin_amdgcn_mfma_f32_16x16x32_bf16(afrag[0][0], bf10, ACC[0][1], 0, 0, 0); \
        ACC[1][0] = __builtin_amdgcn_mfma_f32_16x16x32_bf16(afrag[1][0], bf00, ACC[1][0], 0, 0, 0); \
        ACC[1][1] = __builtin_amdgcn_mfma_f32_16x16x32_bf16(afrag[1][0], bf10, ACC[1][1], 0, 0, 0); \
        ACC[0][0] = __builtin_amdgcn_mfma_f32_16x16x32_bf16(afrag[0][1], bf01, ACC[0][0], 0, 0, 0); \
        ACC[0][1] = __builtin_amdgcn_mfma_f32_16x16x32_bf16(afrag[0][1], bf11, ACC[0][1], 0, 0, 0); \
        ACC[1][0] = __builtin_amdgcn_mfma_f32_16x16x32_bf16(afrag[1][1], bf01, ACC[1][0], 0, 0, 0); \
        ACC[1][1] = __builtin_amdgcn_mfma_f32_16x16x32_bf16(afrag[1][1], bf11, ACC[1][1], 0, 0, 0); \
        __builtin_amdgcn_s_setprio(0);                                        \
    }

    // t = 0: ring slot 0; prologue order makes vmcnt(1) retire stage0+cb.
    GSTEP(0, 16384, acc0, false, acc0, 0, 1)
    // t = 1..63: steady-state vmcnt(1); 21 trips of 3 (slots 1,2,0)
    for (int trip = 0; trip < 21; ++trip) {
        int t1 = 1 + trip * 3;
        GSTEP(8192,  0,     acc1, true, acc0, t1,     1)
        GSTEP(16384, 8192,  acc2, true, acc1, t1 + 1, 1)
        GSTEP(0,     16384, acc0, true, acc2, t1 + 2, 1)
    }
    EPI(acc0)   // final tile's epilogue

    #undef GSTEP
    #undef EPI

    float ls = lsum[0] + lsum[1] + lsum[2] + lsum[3];
    #pragma unroll
    for (int off = 32; off; off >>= 1) ls += __shfl_xor(ls, off);
    if (lane == 0) wsum[w] = ls;
    __syncthreads();
    if (tid == 0) {
        float s = 0.0f;
        #pragma unroll
        for (int i = 0; i < 8; ++i) s += wsum[i];
        atomicAdd(&accs[p], s);
    }
}

__global__ void finalize_kernel(const float* __restrict__ accs,
                                float* __restrict__ out) {
    double inv = 1.0 / (8192.0 * 8192.0 * 3.5449077018110318);
    double mxx = accs[0] * inv, mzz = accs[1] * inv, mxz = accs[2] * inv;
    double mxy = accs[3] * inv, myy = accs[4] * inv, myz = accs[5] * inv;
    double r1 = log(3.0 * sqrt(mxx * mzz + 1e-5) / (mxz + 1e-5));
    double r2 = log(3.0 * sqrt(myy * mzz + 1e-5) / (myz + 1e-5));
    double r3 = log(3.0 * sqrt(mxx * myy + 1e-5) / (mxy + 1e-5));
    out[0] = (float)(10.0 * r1 + r2 + 10.0 * r3);
}

extern "C" void kernel_launch(void* const* d_in, const int* in_sizes, int n_in,
                              void* d_out, int out_size, void* d_ws, size_t ws_size,
                              hipStream_t stream) {
    const float* X = (const float*)d_in[0];
    const float* Y = (const float*)d_in[1];
    const float* Z = (const float*)d_in[2];
    char* ws = (char*)d_ws;
    unsigned short* bmat = (unsigned short*)ws;                       // 3 MB
    float* nscl = (float*)(ws + (size_t)3 * N * D * 2);               // 3*8192 f32
    float* accs = (float*)(ws + (size_t)3 * N * D * 2 + (size_t)3 * N * 4);
    float* out = (float*)d_out;

    hipLaunchKernelGGL(init_accs, dim3(1), dim3(64), 0, stream, accs);
    hipLaunchKernelGGL(convert_norm, dim3(3 * N / 4), dim3(256), 0, stream,
                       X, Y, Z, bmat, nscl);
    hipLaunchKernelGGL(gram_kernel, dim3(128, 6), dim3(512), 0, stream,
                       bmat, nscl, accs);
    hipLaunchKernelGGL(finalize_kernel, dim3(1), dim3(1), 0, stream, accs, out);
}